// Round 14
// baseline (83.517 us; speedup 1.0000x reference)
//
#include <hip/hip_runtime.h>

// NetDensity via corner-stencil scatter + 2D prefix sums.
//   H = prefix_x(prefix_y( sum_n ch_n * ex_n (x) ey_n ))
// Evidence trail:
//  R1/R2: global fp32 atomicAdd memory-side -> none on hot path.
//  R3-R8: LDS strip tiles, bucketed records, 512 balanced blocks.
//  R5->R13 scaling law: scatter time tracks LANE-ATOMIC COUNT 1:1
//         (R8: 16->8 = -23us; R13 conditional snap: 8->~4 = -10.6us).
//  R10: coop fusion 272us (grid.sync ~55us each); replay overhead ~13us.
//  R12: L2-resident packed pins only -3us (permutation = each pin read once;
//       L3 captures reuse anyway).
//  R14: pin-centric bbox: flat_netpin is a permutation and pc==4 uniform ->
//       1 thread/pin, 1 gather each, 4-lane shfl_xor min/max reduction;
//       4x memory parallelism, no CSR serial chain; pack_pins deleted.

#define NBX 256
#define NBY 256
#define CELLS (NBX * NBY)
#define STRIPS 16
#define SROWS 16
#define HALF_TILE (SROWS * NBY)        // 4096 floats (H plane)
#define TILE_FLOATS (HALF_TILE * 2)    // 8192 floats = 32KB
#define NSCAT 512                      // total scatter blocks
#define TOTAL_ENT 724992               // sum of per-strip capacities

#define BS_ 2.0f
#define INV_BS 0.5f
#define SNAP_THR 4096u                 // 32 coord units in fix (x128) units

__constant__ float c_risa[47] = {
    1.0f, 1.0f, 1.0f, 1.0f,
    1.0828f, 1.1536f, 1.2206f, 1.2823f, 1.3385f, 1.3991f, 1.4493f,
    1.6899f, 1.6899f, 1.6899f, 1.6899f, 1.6899f,
    1.8924f, 1.8924f, 1.8924f, 1.8924f, 1.8924f,
    2.0743f, 2.0743f, 2.0743f, 2.0743f, 2.0743f,
    2.2334f, 2.2334f, 2.2334f, 2.2334f, 2.2334f,
    2.3892f, 2.3892f, 2.3892f, 2.3892f, 2.3892f,
    2.5356f, 2.5356f, 2.5356f, 2.5356f, 2.5356f,
    2.6625f, 2.6625f, 2.6625f, 2.6625f, 2.6625f,
    2.7933f};

__constant__ int c_bcnt[STRIPS] = {58,48,39,31,25,21,18,16,
                                   16,18,21,25,31,39,48,58};
__constant__ int c_boff[STRIPS + 1] = {0,58,106,145,176,201,222,240,256,
                                       272,290,311,336,367,406,454,512};
__constant__ int c_cap[STRIPS] = {81920,67584,54272,44032,35840,29696,25600,23552,
                                  23552,25600,29696,35840,44032,54272,67584,81920};
__constant__ int c_loff[STRIPS] = {0,81920,149504,203776,247808,283648,313344,338944,
                                   362496,386048,411648,441344,477184,521216,575488,643072};

// Fixed-point: coord*128 in [0,65535]. bin = v>>8, frac = (v&255)/256.
// Record: .x = xedge_fix, .y = ymin_fix | ymax_fix<<16,
//         .z = ch bits (negated for max-edge), .w = cv bits (same sign).

__device__ __forceinline__ unsigned round_fix(unsigned v) {
    return min((((v + 128u) >> 8) << 8), 65535u);
}

__global__ void zero_cursors(int* __restrict__ cursors) {
    if (threadIdx.x < STRIPS) cursors[threadIdx.x] = 0;
}

// Pass 1 (pin-centric): 1 thread/pin, shfl reduction over the 4-lane group,
// leader lane builds + appends the two edge records (R13 snap logic).
__global__ __launch_bounds__(512) void bbox_pins(
        const float* __restrict__ pin_pos,
        const int* __restrict__ flat_netpin,
        const float* __restrict__ net_weights,
        int4* __restrict__ list, int* __restrict__ cursors, int num_pins) {
    __shared__ int cnt[STRIPS];
    __shared__ int base_[STRIPS];
    int tid = threadIdx.x;
    if (tid < STRIPS) cnt[tid] = 0;
    __syncthreads();

    int j = blockIdx.x * 512 + tid;
    int st0 = -1, st1 = -1, st2 = -1, st3 = -1;
    int p0 = 0, p1 = 0, p2 = 0, p3 = 0;
    int4 r0 = make_int4(0, 0, 0, 0), r1 = make_int4(0, 0, 0, 0);
    if (j < num_pins) {
        int p = flat_netpin[j];
        float2 xy = *reinterpret_cast<const float2*>(pin_pos + 2 * (size_t)p);
        unsigned xf = (unsigned)fminf(fmaxf(rintf(xy.x * 128.0f), 0.0f), 65535.0f);
        unsigned yf = (unsigned)fminf(fmaxf(rintf(xy.y * 128.0f), 0.0f), 65535.0f);
        // 4-lane group min/max (pins 4n..4n+3 sit in 4 consecutive lanes)
        unsigned xo = __shfl_xor((int)xf, 1, 64);
        unsigned xmin = min(xf, xo), xmax = max(xf, xo);
        unsigned yo = __shfl_xor((int)yf, 1, 64);
        unsigned ymin = min(yf, yo), ymax = max(yf, yo);
        xo = __shfl_xor((int)xmin, 2, 64); xmin = min(xmin, xo);
        xo = __shfl_xor((int)xmax, 2, 64); xmax = max(xmax, xo);
        yo = __shfl_xor((int)ymin, 2, 64); ymin = min(ymin, yo);
        yo = __shfl_xor((int)ymax, 2, 64); ymax = max(ymax, yo);

        if ((tid & 3) == 0) {
            int n = j >> 2;                       // netpin_start[n] == 4n (gated)
            float wt = c_risa[4] * net_weights[n];
            float dx = (float)(xmax - xmin) * (1.0f / 128.0f);
            float dy = (float)(ymax - ymin) * (1.0f / 128.0f);
            float ch = (dy > 0.0f) ? wt / fmaxf(dy, 1e-12f) : 0.0f;
            float cv = (dx > 0.0f) ? wt / fmaxf(dx, 1e-12f) : 0.0f;
            if (ch != 0.0f || cv != 0.0f) {
                // Conditional edge snap: err <= 2wt/dy (resp dx) <= wt/16.
                if (ymax - ymin >= SNAP_THR) {
                    ymin = round_fix(ymin);
                    ymax = round_fix(ymax);
                }
                if (xmax - xmin >= SNAP_THR) {
                    xmin = round_fix(xmin);
                    xmax = round_fix(xmax);
                }
                unsigned ypk = ymin | (ymax << 16);
                r0 = make_int4((int)xmin, (int)ypk, __float_as_int(ch), __float_as_int(cv));
                r1 = make_int4((int)xmax, (int)ypk, __float_as_int(-ch), __float_as_int(-cv));
                int k1 = xmin >> 8;
                int k2 = xmax >> 8;
                {
                    st0 = k1 >> 4;
                    p0 = atomicAdd(&cnt[st0], 1);
                    int kb = k1 + 1;
                    if ((xmin & 255u) && kb < 256 && (kb >> 4) != st0) {
                        st1 = kb >> 4; p1 = atomicAdd(&cnt[st1], 1);
                    }
                }
                {
                    st2 = k2 >> 4;
                    p2 = atomicAdd(&cnt[st2], 1);
                    int kb = k2 + 1;
                    if ((xmax & 255u) && kb < 256 && (kb >> 4) != st2) {
                        st3 = kb >> 4; p3 = atomicAdd(&cnt[st3], 1);
                    }
                }
            }
        }
    }
    __syncthreads();
    if (tid < STRIPS) base_[tid] = cnt[tid] ? atomicAdd(&cursors[tid], cnt[tid]) : 0;
    __syncthreads();
    if (st0 >= 0) { int pos = base_[st0] + p0; if (pos < c_cap[st0]) list[c_loff[st0] + pos] = r0; }
    if (st1 >= 0) { int pos = base_[st1] + p1; if (pos < c_cap[st1]) list[c_loff[st1] + pos] = r0; }
    if (st2 >= 0) { int pos = base_[st2] + p2; if (pos < c_cap[st2]) list[c_loff[st2] + pos] = r1; }
    if (st3 >= 0) { int pos = base_[st3] + p3; if (pos < c_cap[st3]) list[c_loff[st3] + pos] = r1; }
}

// Pass 2: LDS strip-tile accumulation. Snapped records: 4 atomics; exact: 8.
__global__ __launch_bounds__(512) void strip_scatter(
        const int4* __restrict__ list, const int* __restrict__ cursors,
        float* __restrict__ P) {
    __shared__ float lds[TILE_FLOATS];   // H plane then V plane
    int bid = blockIdx.x;
    int strip = 0;
#pragma unroll
    for (int s = 1; s < STRIPS; ++s)
        if (bid >= c_boff[s]) strip = s;
    int sub = bid - c_boff[strip];
    int nb = c_bcnt[strip];
    int lo = strip * SROWS;
    int tid = threadIdx.x;
    float4* z = (float4*)lds;
    for (int j = tid; j < TILE_FLOATS / 4; j += 512) z[j] = make_float4(0, 0, 0, 0);
    __syncthreads();

    int len = min(cursors[strip], c_cap[strip]);
    const int4* A = list + c_loff[strip];
    int chunk = (len + nb - 1) / nb;
    int i0 = sub * chunk;
    int i1 = min(i0 + chunk, len);
    for (int i = i0 + tid; i < i1; i += 512) {
        int4 a = A[i];
        unsigned xf = (unsigned)a.x;
        int k = xf >> 8;
        float f = (float)(xf & 255u) * (1.0f / 256.0f);
        int ks = (int)((xf + 128u) >> 8);       // snapped row for H
        unsigned yp = (unsigned)a.y;
        unsigned y1 = yp & 0xffffu, y2 = yp >> 16;
        int j1 = (int)(y1 >> 8);
        float g1 = (float)(y1 & 255u) * (1.0f / 256.0f);
        int j2 = (int)(y2 >> 8);
        float g2 = (float)(y2 & 255u) * (1.0f / 256.0f);
        int js1 = (int)((y1 + 128u) >> 8);      // snapped cols for V
        int js2 = (int)((y2 + 128u) >> 8);
        float sch = __int_as_float(a.z);
        float scv = __int_as_float(a.w);

        // H: one snapped row; 2-pt y edges, fractional second point gated.
        int rh = ks - lo;
        if ((unsigned)rh < SROWS) {
            float w = sch * (BS_ * BS_);
            int rbase = rh * NBY;
            unsafeAtomicAdd(&lds[rbase + j1], w * (1.0f - g1));
            if (g1 > 0.0f && j1 + 1 < NBY)
                unsafeAtomicAdd(&lds[rbase + j1 + 1], w * g1);
            unsafeAtomicAdd(&lds[rbase + j2], -w * (1.0f - g2));
            if (g2 > 0.0f && j2 + 1 < NBY)
                unsafeAtomicAdd(&lds[rbase + j2 + 1], -w * g2);
        }
        // V: 2 snapped y points; row k always, row k+1 gated on fraction.
        if (js1 != js2) {
            float wv = scv * (BS_ * BS_);
            float w0 = wv * (1.0f - f);
            int rr0 = k - lo;
            if ((unsigned)rr0 < SROWS && w0 != 0.0f) {
                int rbase = HALF_TILE + rr0 * NBY;
                if (js1 < NBY) unsafeAtomicAdd(&lds[rbase + js1],  w0);
                if (js2 < NBY) unsafeAtomicAdd(&lds[rbase + js2], -w0);
            }
            if (f > 0.0f) {
                int rr1 = k + 1 - lo;
                if ((unsigned)rr1 < SROWS) {
                    float w1 = wv * f;
                    int rbase = HALF_TILE + rr1 * NBY;
                    if (js1 < NBY) unsafeAtomicAdd(&lds[rbase + js1],  w1);
                    if (js2 < NBY) unsafeAtomicAdd(&lds[rbase + js2], -w1);
                }
            }
        }
    }
    __syncthreads();
    float4* dst = (float4*)(P + (size_t)bid * TILE_FLOATS);
    const float4* src = (const float4*)lds;
    for (int j = tid; j < TILE_FLOATS / 4; j += 512) dst[j] = src[j];
}

// Pass 3: merge this strip's partial tiles + inclusive scan along y.
__global__ void merge_scany(const float* __restrict__ P, float2* __restrict__ T) {
    __shared__ float sh[256];
    __shared__ float sv[256];
    int x = blockIdx.x;
    int t = threadIdx.x;
    int strip = x >> 4;           // SROWS = 16
    int r = x & 15;
    int b0 = c_boff[strip], b1 = c_boff[strip + 1];
    const float* base = P + (size_t)b0 * TILE_FLOATS + r * NBY + t;
    float h = 0.0f, v = 0.0f;
    for (int b = b0; b < b1; ++b) {
        h += base[0];
        v += base[HALF_TILE];
        base += TILE_FLOATS;
    }
    sh[t] = h; sv[t] = v;
    __syncthreads();
    for (int off = 1; off < 256; off <<= 1) {
        float ah = (t >= off) ? sh[t - off] : 0.0f;
        float av = (t >= off) ? sv[t - off] : 0.0f;
        __syncthreads();
        sh[t] += ah;
        sv[t] += av;
        __syncthreads();
    }
    T[x * NBY + t] = make_float2(sh[t], sv[t]);
}

// Pass 4: inclusive scan along x per column y; write the three outputs.
__global__ void scanx_out(const float2* __restrict__ T, float* __restrict__ out) {
    __shared__ float sh[256];
    __shared__ float sv[256];
    int y = blockIdx.x;
    int t = threadIdx.x;          // t = x
    float2 c = T[t * NBY + y];
    sh[t] = c.x; sv[t] = c.y;
    __syncthreads();
    for (int off = 1; off < 256; off <<= 1) {
        float ah = (t >= off) ? sh[t - off] : 0.0f;
        float av = (t >= off) ? sv[t - off] : 0.0f;
        __syncthreads();
        sh[t] += ah;
        sv[t] += av;
        __syncthreads();
    }
    float h = sh[t], v = sv[t];
    int idx = t * NBY + y;
    out[idx] = fabsf(h) + fabsf(v);
    out[CELLS + idx] = h;
    out[2 * CELLS + idx] = v;
}

// ---- fallback (tiny ws or non-uniform CSR): device atomics, dense grid ----
__global__ void zero_dense(float* __restrict__ S) {
    int i = blockIdx.x * blockDim.x + threadIdx.x;
    if (i < CELLS * 2) S[i] = 0.0f;
}

__global__ void fused_atomic(const float* __restrict__ pin_pos,
                             const int* __restrict__ netpin_start,
                             const int* __restrict__ flat_netpin,
                             const float* __restrict__ net_weights,
                             float* __restrict__ S, int num_nets) {
    int n = blockIdx.x * blockDim.x + threadIdx.x;
    if (n >= num_nets) return;
    int s = netpin_start[n];
    int e = netpin_start[n + 1];
    int pc = e - s;
    if (pc <= 0) return;
    float xmin = 1e30f, xmax = -1e30f, ymin = 1e30f, ymax = -1e30f;
    for (int i = s; i < e; ++i) {
        int p = flat_netpin[i];
        float2 xy = *reinterpret_cast<const float2*>(pin_pos + 2 * (long)p);
        xmin = fminf(xmin, xy.x);
        xmax = fmaxf(xmax, xy.x);
        ymin = fminf(ymin, xy.y);
        ymax = fmaxf(ymax, xy.y);
    }
    float wt = c_risa[min(pc, 46)] * net_weights[n];
    float dx = xmax - xmin;
    float dy = ymax - ymin;
    float ch = (dy > 0.0f) ? wt / fmaxf(dy, 1e-12f) : 0.0f;
    float cv = (dx > 0.0f) ? wt / fmaxf(dx, 1e-12f) : 0.0f;
    if (ch == 0.0f && cv == 0.0f) return;
    float t1 = xmin * INV_BS, t2 = xmax * INV_BS;
    int k1 = min(max((int)floorf(t1), 0), 256);
    int k2 = min(max((int)floorf(t2), 0), 256);
    float fx1 = t1 - k1, fx2 = t2 - k2;
    float u1 = ymin * INV_BS, u2 = ymax * INV_BS;
    int j1 = min(max((int)floorf(u1), 0), 256);
    int j2 = min(max((int)floorf(u2), 0), 256);
    float fy1 = u1 - j1, fy2 = u2 - j2;
    int   xi[4] = {k1, k1 + 1, k2, k2 + 1};
    float xw[4] = {BS_ * (1 - fx1), BS_ * fx1, -BS_ * (1 - fx2), -BS_ * fx2};
    int   yi[4] = {j1, j1 + 1, j2, j2 + 1};
    float yw[4] = {BS_ * (1 - fy1), BS_ * fy1, -BS_ * (1 - fy2), -BS_ * fy2};
#pragma unroll
    for (int a = 0; a < 4; ++a) {
        if (xi[a] >= NBX) continue;
        int rbase = xi[a] * NBY;
        float wh = ch * xw[a];
        float wv = cv * xw[a];
#pragma unroll
        for (int b = 0; b < 4; ++b) {
            if (yi[b] >= NBY) continue;
            int off = rbase + yi[b];
            atomicAdd(&S[off], wh * yw[b]);
            atomicAdd(&S[off + CELLS], wv * yw[b]);
        }
    }
}

__global__ void scany_dense(const float* __restrict__ S, float2* __restrict__ T) {
    __shared__ float sh[256];
    __shared__ float sv[256];
    int x = blockIdx.x;
    int t = threadIdx.x;
    sh[t] = S[x * NBY + t];
    sv[t] = S[CELLS + x * NBY + t];
    __syncthreads();
    for (int off = 1; off < 256; off <<= 1) {
        float ah = (t >= off) ? sh[t - off] : 0.0f;
        float av = (t >= off) ? sv[t - off] : 0.0f;
        __syncthreads();
        sh[t] += ah;
        sv[t] += av;
        __syncthreads();
    }
    T[x * NBY + t] = make_float2(sh[t], sv[t]);
}

static inline size_t alignup(size_t v, size_t a) { return (v + a - 1) & ~(a - 1); }

extern "C" void kernel_launch(void* const* d_in, const int* in_sizes, int n_in,
                              void* d_out, int out_size, void* d_ws, size_t ws_size,
                              hipStream_t stream) {
    const float* pin_pos = (const float*)d_in[0];
    const int* netpin_start = (const int*)d_in[1];
    const int* flat_netpin = (const int*)d_in[2];
    const float* net_weights = (const float*)d_in[3];
    int num_nets = in_sizes[1] - 1;
    int num_pins = in_sizes[2];

    size_t off = 0;
    size_t list_off = off; off = alignup(off + (size_t)TOTAL_ENT * 16, 16);
    size_t P_off = off;    off = alignup(off + (size_t)NSCAT * TILE_FLOATS * 4, 16);
    size_t T_off = off;    off = alignup(off + (size_t)CELLS * 8, 16);
    size_t cur_off = off;  off += 256;
    size_t need = off;

    float* out = (float*)d_out;
    char* ws = (char*)d_ws;

    // Fast path requires the uniform 4-pin CSR (pin j -> net j>>2).
    if (ws_size >= need && num_nets <= 262144 && num_pins == 4 * num_nets) {
        int4* list = (int4*)(ws + list_off);
        float* P = (float*)(ws + P_off);
        float2* T = (float2*)(ws + T_off);
        int* cursors = (int*)(ws + cur_off);
        zero_cursors<<<1, 64, 0, stream>>>(cursors);
        bbox_pins<<<(num_pins + 511) / 512, 512, 0, stream>>>(
            pin_pos, flat_netpin, net_weights, list, cursors, num_pins);
        strip_scatter<<<NSCAT, 512, 0, stream>>>(list, cursors, P);
        merge_scany<<<NBX, 256, 0, stream>>>(P, T);
        scanx_out<<<NBY, 256, 0, stream>>>(T, out);
    } else {
        float* S = (float*)ws;
        float2* T = (float2*)(ws + (size_t)CELLS * 2 * sizeof(float));
        int nb = (num_nets + 255) / 256;
        zero_dense<<<(CELLS * 2 + 255) / 256, 256, 0, stream>>>(S);
        fused_atomic<<<nb, 256, 0, stream>>>(pin_pos, netpin_start, flat_netpin,
                                             net_weights, S, num_nets);
        scany_dense<<<NBX, 256, 0, stream>>>(S, T);
        scanx_out<<<NBY, 256, 0, stream>>>(T, out);
    }
}

// Round 15
// 70.354 us; speedup vs baseline: 1.1871x; 1.1871x over previous
//
#include <hip/hip_runtime.h>

// NetDensity via corner-stencil scatter + 2D prefix sums.
//   H = prefix_x(prefix_y( sum_n ch_n * ex_n (x) ey_n ))
// Evidence trail:
//  R1/R2: global fp32 atomicAdd memory-side -> none on hot path.
//  R3-R8: LDS strip tiles, bucketed records, 512 balanced blocks.
//  R5->R13 scaling law: scatter time tracks LANE-ATOMIC COUNT 1:1
//         (R8: 16->8 = -23us; R13 conditional snap: 8->~4 = -10.6us).
//  R10: coop fusion 272us (grid.sync ~55us each); replay overhead ~13us.
//  R12: L2-resident packed pins (4MB table).
//  R13: conditional edge snap (err <= 2wt/dy resp 2wt/dx, safe for
//       dy,dx >= 32; tiny-bbox nets keep exact path) -> ~4 atomics/record.
//       70.75us, absmax 32. CHAMPION.
//  R14: pin-centric bbox REGRESSED (+12.8us: raw 8MB gathers + shfl lockstep
//       + leader-lane divergence). R15: revert to R13 verbatim.

#define NBX 256
#define NBY 256
#define CELLS (NBX * NBY)
#define STRIPS 16
#define SROWS 16
#define HALF_TILE (SROWS * NBY)        // 4096 floats (H plane)
#define TILE_FLOATS (HALF_TILE * 2)    // 8192 floats = 32KB
#define NSCAT 512                      // total scatter blocks
#define TOTAL_ENT 724992               // sum of per-strip capacities

#define BS_ 2.0f
#define INV_BS 0.5f
#define SNAP_THR 4096u                 // 32 coord units in fix (x128) units

__constant__ float c_risa[47] = {
    1.0f, 1.0f, 1.0f, 1.0f,
    1.0828f, 1.1536f, 1.2206f, 1.2823f, 1.3385f, 1.3991f, 1.4493f,
    1.6899f, 1.6899f, 1.6899f, 1.6899f, 1.6899f,
    1.8924f, 1.8924f, 1.8924f, 1.8924f, 1.8924f,
    2.0743f, 2.0743f, 2.0743f, 2.0743f, 2.0743f,
    2.2334f, 2.2334f, 2.2334f, 2.2334f, 2.2334f,
    2.3892f, 2.3892f, 2.3892f, 2.3892f, 2.3892f,
    2.5356f, 2.5356f, 2.5356f, 2.5356f, 2.5356f,
    2.6625f, 2.6625f, 2.6625f, 2.6625f, 2.6625f,
    2.7933f};

__constant__ int c_bcnt[STRIPS] = {58,48,39,31,25,21,18,16,
                                   16,18,21,25,31,39,48,58};
__constant__ int c_boff[STRIPS + 1] = {0,58,106,145,176,201,222,240,256,
                                       272,290,311,336,367,406,454,512};
__constant__ int c_cap[STRIPS] = {81920,67584,54272,44032,35840,29696,25600,23552,
                                  23552,25600,29696,35840,44032,54272,67584,81920};
__constant__ int c_loff[STRIPS] = {0,81920,149504,203776,247808,283648,313344,338944,
                                   362496,386048,411648,441344,477184,521216,575488,643072};

// Fixed-point: coord*128 in [0,65535]. bin = v>>8, frac = (v&255)/256.
// Record: .x = xedge_fix, .y = ymin_fix | ymax_fix<<16,
//         .z = ch bits (negated for max-edge), .w = cv bits (same sign).

__device__ __forceinline__ unsigned round_fix(unsigned v) {
    return min((((v + 128u) >> 8) << 8), 65535u);
}

// Pass 0: pack pins to u32 {y_fix<<16 | x_fix} (4MB, L2-resident) + zero cursors.
__global__ __launch_bounds__(256) void pack_pins(
        const float* __restrict__ pin_pos, unsigned* __restrict__ ppack,
        int* __restrict__ cursors, int num_pins) {
    int i = blockIdx.x * 256 + threadIdx.x;
    if (blockIdx.x == 0 && threadIdx.x < STRIPS) cursors[threadIdx.x] = 0;
    if (i >= num_pins) return;
    float2 xy = *reinterpret_cast<const float2*>(pin_pos + 2 * (size_t)i);
    float xr = fminf(fmaxf(rintf(xy.x * 128.0f), 0.0f), 65535.0f);
    float yr = fminf(fmaxf(rintf(xy.y * 128.0f), 0.0f), 65535.0f);
    ppack[i] = (unsigned)xr | ((unsigned)yr << 16);
}

// Pass 1: bbox (integer min/max) -> conditional edge-snap -> two edge records
// appended (block-aggregated) into the strip lists.
__global__ __launch_bounds__(256) void bbox_lists(
        const unsigned* __restrict__ ppack,
        const int* __restrict__ netpin_start,
        const int* __restrict__ flat_netpin,
        const float* __restrict__ net_weights,
        int4* __restrict__ list, int* __restrict__ cursors, int num_nets) {
    __shared__ int cnt[STRIPS];
    __shared__ int base_[STRIPS];
    int tid = threadIdx.x;
    if (tid < STRIPS) cnt[tid] = 0;
    __syncthreads();

    int n = blockIdx.x * 256 + tid;
    int st0 = -1, st1 = -1, st2 = -1, st3 = -1;
    int p0 = 0, p1 = 0, p2 = 0, p3 = 0;
    int4 r0 = make_int4(0, 0, 0, 0), r1 = make_int4(0, 0, 0, 0);
    if (n < num_nets) {
        int s = netpin_start[n];
        int e = netpin_start[n + 1];
        int pc = e - s;
        unsigned xmin = 65535u, xmax = 0u, ymin = 65535u, ymax = 0u;
        if (pc == 4 && (s & 3) == 0) {
            int4 pid = *reinterpret_cast<const int4*>(flat_netpin + s);
            unsigned q0 = ppack[pid.x];
            unsigned q1 = ppack[pid.y];
            unsigned q2 = ppack[pid.z];
            unsigned q3 = ppack[pid.w];
            unsigned x0 = q0 & 0xffffu, x1 = q1 & 0xffffu;
            unsigned x2 = q2 & 0xffffu, x3 = q3 & 0xffffu;
            unsigned v0 = q0 >> 16, v1 = q1 >> 16, v2 = q2 >> 16, v3 = q3 >> 16;
            xmin = min(min(x0, x1), min(x2, x3));
            xmax = max(max(x0, x1), max(x2, x3));
            ymin = min(min(v0, v1), min(v2, v3));
            ymax = max(max(v0, v1), max(v2, v3));
        } else {
            for (int i = s; i < e; ++i) {
                int p = flat_netpin[i];
                unsigned q = ppack[p];
                unsigned x = q & 0xffffu, y = q >> 16;
                xmin = min(xmin, x); xmax = max(xmax, x);
                ymin = min(ymin, y); ymax = max(ymax, y);
            }
        }
        if (pc > 0) {
            float wt = c_risa[min(pc, 46)] * net_weights[n];
            float dx = (float)(xmax - xmin) * (1.0f / 128.0f);
            float dy = (float)(ymax - ymin) * (1.0f / 128.0f);
            float ch = (dy > 0.0f) ? wt / fmaxf(dy, 1e-12f) : 0.0f;
            float cv = (dx > 0.0f) ? wt / fmaxf(dx, 1e-12f) : 0.0f;
            if (ch != 0.0f || cv != 0.0f) {
                // Conditional edge snap: err <= 2wt/dy (resp dx) <= wt/16.
                if (ymax - ymin >= SNAP_THR) {
                    ymin = round_fix(ymin);
                    ymax = round_fix(ymax);
                }
                if (xmax - xmin >= SNAP_THR) {
                    xmin = round_fix(xmin);
                    xmax = round_fix(xmax);
                }
                unsigned ypk = ymin | (ymax << 16);
                r0 = make_int4((int)xmin, (int)ypk, __float_as_int(ch), __float_as_int(cv));
                r1 = make_int4((int)xmax, (int)ypk, __float_as_int(-ch), __float_as_int(-cv));
                int k1 = xmin >> 8;
                int k2 = xmax >> 8;
                {
                    st0 = k1 >> 4;
                    p0 = atomicAdd(&cnt[st0], 1);
                    int kb = k1 + 1;
                    // straddle only when the edge has a fractional part
                    if ((xmin & 255u) && kb < 256 && (kb >> 4) != st0) {
                        st1 = kb >> 4; p1 = atomicAdd(&cnt[st1], 1);
                    }
                }
                {
                    st2 = k2 >> 4;
                    p2 = atomicAdd(&cnt[st2], 1);
                    int kb = k2 + 1;
                    if ((xmax & 255u) && kb < 256 && (kb >> 4) != st2) {
                        st3 = kb >> 4; p3 = atomicAdd(&cnt[st3], 1);
                    }
                }
            }
        }
    }
    __syncthreads();
    if (tid < STRIPS) base_[tid] = cnt[tid] ? atomicAdd(&cursors[tid], cnt[tid]) : 0;
    __syncthreads();
    if (st0 >= 0) { int pos = base_[st0] + p0; if (pos < c_cap[st0]) list[c_loff[st0] + pos] = r0; }
    if (st1 >= 0) { int pos = base_[st1] + p1; if (pos < c_cap[st1]) list[c_loff[st1] + pos] = r0; }
    if (st2 >= 0) { int pos = base_[st2] + p2; if (pos < c_cap[st2]) list[c_loff[st2] + pos] = r1; }
    if (st3 >= 0) { int pos = base_[st3] + p3; if (pos < c_cap[st3]) list[c_loff[st3] + pos] = r1; }
}

// Pass 2: LDS strip-tile accumulation. Snapped records: 4 atomics; exact: 8.
__global__ __launch_bounds__(512) void strip_scatter(
        const int4* __restrict__ list, const int* __restrict__ cursors,
        float* __restrict__ P) {
    __shared__ float lds[TILE_FLOATS];   // H plane then V plane
    int bid = blockIdx.x;
    int strip = 0;
#pragma unroll
    for (int s = 1; s < STRIPS; ++s)
        if (bid >= c_boff[s]) strip = s;
    int sub = bid - c_boff[strip];
    int nb = c_bcnt[strip];
    int lo = strip * SROWS;
    int tid = threadIdx.x;
    float4* z = (float4*)lds;
    for (int j = tid; j < TILE_FLOATS / 4; j += 512) z[j] = make_float4(0, 0, 0, 0);
    __syncthreads();

    int len = min(cursors[strip], c_cap[strip]);
    const int4* A = list + c_loff[strip];
    int chunk = (len + nb - 1) / nb;
    int i0 = sub * chunk;
    int i1 = min(i0 + chunk, len);
    for (int i = i0 + tid; i < i1; i += 512) {
        int4 a = A[i];
        unsigned xf = (unsigned)a.x;
        int k = xf >> 8;
        float f = (float)(xf & 255u) * (1.0f / 256.0f);
        int ks = (int)((xf + 128u) >> 8);       // snapped row for H
        unsigned yp = (unsigned)a.y;
        unsigned y1 = yp & 0xffffu, y2 = yp >> 16;
        int j1 = (int)(y1 >> 8);
        float g1 = (float)(y1 & 255u) * (1.0f / 256.0f);
        int j2 = (int)(y2 >> 8);
        float g2 = (float)(y2 & 255u) * (1.0f / 256.0f);
        int js1 = (int)((y1 + 128u) >> 8);      // snapped cols for V
        int js2 = (int)((y2 + 128u) >> 8);
        float sch = __int_as_float(a.z);
        float scv = __int_as_float(a.w);

        // H: one snapped row; 2-pt y edges, fractional second point gated.
        int rh = ks - lo;
        if ((unsigned)rh < SROWS) {
            float w = sch * (BS_ * BS_);
            int rbase = rh * NBY;
            unsafeAtomicAdd(&lds[rbase + j1], w * (1.0f - g1));
            if (g1 > 0.0f && j1 + 1 < NBY)
                unsafeAtomicAdd(&lds[rbase + j1 + 1], w * g1);
            unsafeAtomicAdd(&lds[rbase + j2], -w * (1.0f - g2));
            if (g2 > 0.0f && j2 + 1 < NBY)
                unsafeAtomicAdd(&lds[rbase + j2 + 1], -w * g2);
        }
        // V: 2 snapped y points; row k always, row k+1 gated on fraction.
        if (js1 != js2) {
            float wv = scv * (BS_ * BS_);
            float w0 = wv * (1.0f - f);
            int rr0 = k - lo;
            if ((unsigned)rr0 < SROWS && w0 != 0.0f) {
                int rbase = HALF_TILE + rr0 * NBY;
                if (js1 < NBY) unsafeAtomicAdd(&lds[rbase + js1],  w0);
                if (js2 < NBY) unsafeAtomicAdd(&lds[rbase + js2], -w0);
            }
            if (f > 0.0f) {
                int rr1 = k + 1 - lo;
                if ((unsigned)rr1 < SROWS) {
                    float w1 = wv * f;
                    int rbase = HALF_TILE + rr1 * NBY;
                    if (js1 < NBY) unsafeAtomicAdd(&lds[rbase + js1],  w1);
                    if (js2 < NBY) unsafeAtomicAdd(&lds[rbase + js2], -w1);
                }
            }
        }
    }
    __syncthreads();
    float4* dst = (float4*)(P + (size_t)bid * TILE_FLOATS);
    const float4* src = (const float4*)lds;
    for (int j = tid; j < TILE_FLOATS / 4; j += 512) dst[j] = src[j];
}

// Pass 3: merge this strip's partial tiles + inclusive scan along y.
__global__ void merge_scany(const float* __restrict__ P, float2* __restrict__ T) {
    __shared__ float sh[256];
    __shared__ float sv[256];
    int x = blockIdx.x;
    int t = threadIdx.x;
    int strip = x >> 4;           // SROWS = 16
    int r = x & 15;
    int b0 = c_boff[strip], b1 = c_boff[strip + 1];
    const float* base = P + (size_t)b0 * TILE_FLOATS + r * NBY + t;
    float h = 0.0f, v = 0.0f;
    for (int b = b0; b < b1; ++b) {
        h += base[0];
        v += base[HALF_TILE];
        base += TILE_FLOATS;
    }
    sh[t] = h; sv[t] = v;
    __syncthreads();
    for (int off = 1; off < 256; off <<= 1) {
        float ah = (t >= off) ? sh[t - off] : 0.0f;
        float av = (t >= off) ? sv[t - off] : 0.0f;
        __syncthreads();
        sh[t] += ah;
        sv[t] += av;
        __syncthreads();
    }
    T[x * NBY + t] = make_float2(sh[t], sv[t]);
}

// Pass 4: inclusive scan along x per column y; write the three outputs.
__global__ void scanx_out(const float2* __restrict__ T, float* __restrict__ out) {
    __shared__ float sh[256];
    __shared__ float sv[256];
    int y = blockIdx.x;
    int t = threadIdx.x;          // t = x
    float2 c = T[t * NBY + y];
    sh[t] = c.x; sv[t] = c.y;
    __syncthreads();
    for (int off = 1; off < 256; off <<= 1) {
        float ah = (t >= off) ? sh[t - off] : 0.0f;
        float av = (t >= off) ? sv[t - off] : 0.0f;
        __syncthreads();
        sh[t] += ah;
        sv[t] += av;
        __syncthreads();
    }
    float h = sh[t], v = sv[t];
    int idx = t * NBY + y;
    out[idx] = fabsf(h) + fabsf(v);
    out[CELLS + idx] = h;
    out[2 * CELLS + idx] = v;
}

// ---- fallback (tiny ws or unexpected shape): device atomics, dense grid ----
__global__ void zero_dense(float* __restrict__ S) {
    int i = blockIdx.x * blockDim.x + threadIdx.x;
    if (i < CELLS * 2) S[i] = 0.0f;
}

__global__ void fused_atomic(const float* __restrict__ pin_pos,
                             const int* __restrict__ netpin_start,
                             const int* __restrict__ flat_netpin,
                             const float* __restrict__ net_weights,
                             float* __restrict__ S, int num_nets) {
    int n = blockIdx.x * blockDim.x + threadIdx.x;
    if (n >= num_nets) return;
    int s = netpin_start[n];
    int e = netpin_start[n + 1];
    int pc = e - s;
    if (pc <= 0) return;
    float xmin = 1e30f, xmax = -1e30f, ymin = 1e30f, ymax = -1e30f;
    for (int i = s; i < e; ++i) {
        int p = flat_netpin[i];
        float2 xy = *reinterpret_cast<const float2*>(pin_pos + 2 * (long)p);
        xmin = fminf(xmin, xy.x);
        xmax = fmaxf(xmax, xy.x);
        ymin = fminf(ymin, xy.y);
        ymax = fmaxf(ymax, xy.y);
    }
    float wt = c_risa[min(pc, 46)] * net_weights[n];
    float dx = xmax - xmin;
    float dy = ymax - ymin;
    float ch = (dy > 0.0f) ? wt / fmaxf(dy, 1e-12f) : 0.0f;
    float cv = (dx > 0.0f) ? wt / fmaxf(dx, 1e-12f) : 0.0f;
    if (ch == 0.0f && cv == 0.0f) return;
    float t1 = xmin * INV_BS, t2 = xmax * INV_BS;
    int k1 = min(max((int)floorf(t1), 0), 256);
    int k2 = min(max((int)floorf(t2), 0), 256);
    float fx1 = t1 - k1, fx2 = t2 - k2;
    float u1 = ymin * INV_BS, u2 = ymax * INV_BS;
    int j1 = min(max((int)floorf(u1), 0), 256);
    int j2 = min(max((int)floorf(u2), 0), 256);
    float fy1 = u1 - j1, fy2 = u2 - j2;
    int   xi[4] = {k1, k1 + 1, k2, k2 + 1};
    float xw[4] = {BS_ * (1 - fx1), BS_ * fx1, -BS_ * (1 - fx2), -BS_ * fx2};
    int   yi[4] = {j1, j1 + 1, j2, j2 + 1};
    float yw[4] = {BS_ * (1 - fy1), BS_ * fy1, -BS_ * (1 - fy2), -BS_ * fy2};
#pragma unroll
    for (int a = 0; a < 4; ++a) {
        if (xi[a] >= NBX) continue;
        int rbase = xi[a] * NBY;
        float wh = ch * xw[a];
        float wv = cv * xw[a];
#pragma unroll
        for (int b = 0; b < 4; ++b) {
            if (yi[b] >= NBY) continue;
            int off = rbase + yi[b];
            atomicAdd(&S[off], wh * yw[b]);
            atomicAdd(&S[off + CELLS], wv * yw[b]);
        }
    }
}

__global__ void scany_dense(const float* __restrict__ S, float2* __restrict__ T) {
    __shared__ float sh[256];
    __shared__ float sv[256];
    int x = blockIdx.x;
    int t = threadIdx.x;
    sh[t] = S[x * NBY + t];
    sv[t] = S[CELLS + x * NBY + t];
    __syncthreads();
    for (int off = 1; off < 256; off <<= 1) {
        float ah = (t >= off) ? sh[t - off] : 0.0f;
        float av = (t >= off) ? sv[t - off] : 0.0f;
        __syncthreads();
        sh[t] += ah;
        sv[t] += av;
        __syncthreads();
    }
    T[x * NBY + t] = make_float2(sh[t], sv[t]);
}

static inline size_t alignup(size_t v, size_t a) { return (v + a - 1) & ~(a - 1); }

extern "C" void kernel_launch(void* const* d_in, const int* in_sizes, int n_in,
                              void* d_out, int out_size, void* d_ws, size_t ws_size,
                              hipStream_t stream) {
    const float* pin_pos = (const float*)d_in[0];
    const int* netpin_start = (const int*)d_in[1];
    const int* flat_netpin = (const int*)d_in[2];
    const float* net_weights = (const float*)d_in[3];
    int num_nets = in_sizes[1] - 1;
    int num_pins = in_sizes[2];

    size_t off = 0;
    size_t pk_off = off;   off = alignup(off + (size_t)num_pins * 4, 16);
    size_t list_off = off; off = alignup(off + (size_t)TOTAL_ENT * 16, 16);
    size_t P_off = off;    off = alignup(off + (size_t)NSCAT * TILE_FLOATS * 4, 16);
    size_t T_off = off;    off = alignup(off + (size_t)CELLS * 8, 16);
    size_t cur_off = off;  off += 256;
    size_t need = off;

    float* out = (float*)d_out;
    char* ws = (char*)d_ws;
    int nb = (num_nets + 255) / 256;

    if (ws_size >= need && num_nets <= 262144) {
        unsigned* ppack = (unsigned*)(ws + pk_off);
        int4* list = (int4*)(ws + list_off);
        float* P = (float*)(ws + P_off);
        float2* T = (float2*)(ws + T_off);
        int* cursors = (int*)(ws + cur_off);
        pack_pins<<<(num_pins + 255) / 256, 256, 0, stream>>>(pin_pos, ppack,
                                                              cursors, num_pins);
        bbox_lists<<<nb, 256, 0, stream>>>(ppack, netpin_start, flat_netpin,
                                           net_weights, list, cursors, num_nets);
        strip_scatter<<<NSCAT, 512, 0, stream>>>(list, cursors, P);
        merge_scany<<<NBX, 256, 0, stream>>>(P, T);
        scanx_out<<<NBY, 256, 0, stream>>>(T, out);
    } else {
        float* S = (float*)ws;
        float2* T = (float2*)(ws + (size_t)CELLS * 2 * sizeof(float));
        zero_dense<<<(CELLS * 2 + 255) / 256, 256, 0, stream>>>(S);
        fused_atomic<<<nb, 256, 0, stream>>>(pin_pos, netpin_start, flat_netpin,
                                             net_weights, S, num_nets);
        scany_dense<<<NBX, 256, 0, stream>>>(S, T);
        scanx_out<<<NBY, 256, 0, stream>>>(T, out);
    }
}